// Round 3
// baseline (144.267 us; speedup 1.0000x reference)
//
#include <hip/hip_runtime.h>

#define NPIX 409600   // 640*640
#define NB 8          // batch

// ---------------- workspace layout (4-byte words, per batch) ----------------
constexpr int OFF_H0    = 0;     // 2048 u32  level-0 histogram (key bits 31..21)
constexpr int OFF_H1    = 2048;  // 2048 u32  level-1 histogram (key bits 20..10)
constexpr int OFF_H2    = 4096;  // 1024 u32  level-2 histogram (key bits 9..0)
constexpr int OFF_KC    = 5120;  // 8 u32     kernel-mask counts per instance
constexpr int OFF_TC    = 5128;  // 8 u32     text-mask counts per instance
constexpr int OFF_KS    = 5136;  // 32 f32    kernel-mask sim sums (inst*4+c)
constexpr int OFF_AGG   = 5168;  // 8 f32     per-instance sum log1p(D)
constexpr int OFF_CPOS  = 5176;  // u32
constexpr int OFF_CPOSM = 5177;  // u32  pos & tm<=0.5
constexpr int OFF_NEGNUM= 5179;  // u32
constexpr int OFF_PFX0  = 5180;  // u32
constexpr int OFF_K1    = 5181;  // u32
constexpr int OFF_PFX1  = 5182;  // u32
constexpr int OFF_K2    = 5183;  // u32
constexpr int OFF_TH    = 5184;  // f32  OHEM threshold
constexpr int OFF_FALL  = 5185;  // u32  fallback flag
constexpr int OFF_G     = 5186;  // 32 f32 centroids
constexpr int OFF_NV    = 5218;  // u32 n_valid
constexpr int OFF_VM    = 5219;  // u32 valid bitmask
constexpr int OFF_LDIS  = 5220;  // f32
constexpr int OFF_DICE  = 5221;  // 6 f32: at,bt,ct,ak,bk,ck
constexpr int OFF_KN    = 5227;  // u32 compact key count
constexpr int PER_BATCH = 5376;  // padded
constexpr int KEYS_BASE = NB * PER_BATCH;  // compact key arrays start here (words)

// map float -> uint monotone ascending (larger float -> larger key)
__device__ __forceinline__ unsigned mapf(float s) {
  unsigned b = __float_as_uint(s);
  return (b & 0x80000000u) ? ~b : (b | 0x80000000u);
}
__device__ __forceinline__ float unmapf(unsigned u) {
  return __uint_as_float((u & 0x80000000u) ? (u & 0x7FFFFFFFu) : ~u);
}

__device__ __forceinline__ float wredf(float v) {
#pragma unroll
  for (int m = 32; m >= 1; m >>= 1) v += __shfl_xor(v, m, 64);
  return v;
}
__device__ __forceinline__ unsigned wredu(unsigned v) {
#pragma unroll
  for (int m = 32; m >= 1; m >>= 1) v += (unsigned)__shfl_xor((int)v, m, 64);
  return v;
}

// ---------------- pass A: per-pixel stats + level-0 hist + key compaction ----
// R2 lesson: register accumulator arrays (42 regs) got AGPR-evicted (VGPR=48
// reported) -> v_accvgpr churn per pixel. Replace with 16-way replicated LDS
// atomics: ~6 ds_add per pixel, ~4 lanes/replica collision.
template <bool COMPACT>
__global__ __launch_bounds__(256, 4) void kA(const float* __restrict__ out_,
                                             const int* __restrict__ lab_,
                                             const float* __restrict__ tm_,
                                             unsigned* __restrict__ ws) {
  const int b = blockIdx.y;
  unsigned* wsb = ws + (size_t)b * PER_BATCH;
  float* wsbf = (float*)wsb;
  __shared__ unsigned sh_h[2048];
  __shared__ unsigned sh_kc[112], sh_tc[112];   // [inst 0..6][replica 0..15]
  __shared__ float sh_ks[448];                  // [c 0..3][inst][replica]
  __shared__ unsigned sh_c[2];
  __shared__ unsigned sh_kn;
  __shared__ unsigned sh_gbase;
  __shared__ unsigned sh_keys[2048];            // block covers exactly 2048 px
  const int tid = threadIdx.x;
  const int rep = tid & 15;
  const int lane = tid & 63;
  for (int i = tid; i < 2048; i += 256) sh_h[i] = 0u;
  for (int i = tid; i < 112; i += 256) { sh_kc[i] = 0u; sh_tc[i] = 0u; }
  for (int i = tid; i < 448; i += 256) sh_ks[i] = 0.f;
  if (tid < 2) sh_c[tid] = 0u;
  if (tid == 0) sh_kn = 0u;
  __syncthreads();

  const float4* tx = (const float4*)(out_ + (size_t)b * 6 * NPIX);
  const float4* s0 = (const float4*)(out_ + (size_t)b * 6 * NPIX + 2 * (size_t)NPIX);
  const float4* s1 = (const float4*)(out_ + (size_t)b * 6 * NPIX + 3 * (size_t)NPIX);
  const float4* s2 = (const float4*)(out_ + (size_t)b * 6 * NPIX + 4 * (size_t)NPIX);
  const float4* s3 = (const float4*)(out_ + (size_t)b * 6 * NPIX + 5 * (size_t)NPIX);
  const int4* gt = (const int4*)(lab_ + (size_t)b * 2 * NPIX);
  const int4* gk = (const int4*)(lab_ + (size_t)b * 2 * NPIX + NPIX);
  const float4* tmv = (const float4*)(tm_ + (size_t)b * NPIX);

  unsigned cpos = 0, cposm = 0;
  // exactly 2 iterations: gridDim.x = 200, 51200 threads/batch, nv = 102400
#pragma unroll
  for (int it = 0; it < 2; ++it) {
    const int i = it * 51200 + blockIdx.x * 256 + tid;
    float4 t4 = tx[i]; int4 g4 = gt[i]; int4 k4 = gk[i]; float4 m4 = tmv[i];
    float4 a0 = s0[i], a1 = s1[i], a2 = s2[i], a3 = s3[i];
#pragma unroll
    for (int j = 0; j < 4; ++j) {
      float tv = ((const float*)&t4)[j];
      int gtv = ((const int*)&g4)[j];
      int gkv = ((const int*)&k4)[j];
      float mv = ((const float*)&m4)[j];
      bool pos = gtv > 0;
      cpos += pos;
      cposm += (pos && (mv <= 0.5f));
      unsigned key = mapf(tv);
      if (!pos) atomicAdd(&sh_h[key >> 21], 1u);
      else      atomicAdd(&sh_tc[(gtv - 1) * 16 + rep], 1u);
      if (gkv > 0) {
        int base = (gkv - 1) * 16 + rep;
        atomicAdd(&sh_kc[base], 1u);
        atomicAdd(&sh_ks[0 * 112 + base], ((const float*)&a0)[j]);
        atomicAdd(&sh_ks[1 * 112 + base], ((const float*)&a1)[j]);
        atomicAdd(&sh_ks[2 * 112 + base], ((const float*)&a2)[j]);
        atomicAdd(&sh_ks[3 * 112 + base], ((const float*)&a3)[j]);
      }
      if (COMPACT) {
        unsigned long long mask = __ballot(!pos);
        unsigned cnt = (unsigned)__popcll(mask);
        unsigned wbase = 0;
        if (lane == 0 && cnt) wbase = atomicAdd(&sh_kn, cnt);
        wbase = (unsigned)__shfl((int)wbase, 0, 64);
        if (!pos) {
          unsigned ofs = (unsigned)__popcll(mask & ((1ull << lane) - 1ull));
          sh_keys[wbase + ofs] = key;
        }
      }
    }
  }

  unsigned r;
  r = wredu(cpos);  if (lane == 0) atomicAdd(&sh_c[0], r);
  r = wredu(cposm); if (lane == 0) atomicAdd(&sh_c[1], r);
  __syncthreads();

  for (int i = tid; i < 2048; i += 256) {
    unsigned v = sh_h[i]; if (v) atomicAdd(&wsb[OFF_H0 + i], v);
  }
  if (tid < 7) {
    unsigned s = 0;
#pragma unroll
    for (int q = 0; q < 16; ++q) s += sh_kc[tid * 16 + q];
    if (s) atomicAdd(&wsb[OFF_KC + 1 + tid], s);
  } else if (tid < 14) {
    int k = tid - 7; unsigned s = 0;
#pragma unroll
    for (int q = 0; q < 16; ++q) s += sh_tc[k * 16 + q];
    if (s) atomicAdd(&wsb[OFF_TC + 1 + k], s);
  } else if (tid < 42) {
    int t = tid - 14; int c = t / 7, k = t % 7;
    float s = 0.f;
#pragma unroll
    for (int q = 0; q < 16; ++q) s += sh_ks[c * 112 + k * 16 + q];
    if (s != 0.f) atomicAdd(&wsbf[OFF_KS + 4 + k * 4 + c], s);
  }
  if (tid == 0) {
    atomicAdd(&wsb[OFF_CPOS], sh_c[0]);
    atomicAdd(&wsb[OFF_CPOSM], sh_c[1]);
  }
  if (COMPACT) {
    if (tid == 0) sh_gbase = atomicAdd(&wsb[OFF_KN], sh_kn);
    __syncthreads();
    unsigned g = sh_gbase, n = sh_kn;
    unsigned* keys = ws + KEYS_BASE + (size_t)b * NPIX;
    for (unsigned i = tid; i < n; i += 256) keys[g + i] = sh_keys[i];
  }
}

// ------- pass B: scalars, centroids, loss_dis, parallel scan level-0 -------
__global__ void kB(unsigned* __restrict__ ws) {
  const int b = blockIdx.x;
  unsigned* wsb = ws + (size_t)b * PER_BATCH;
  float* wsbf = (float*)wsb;
  __shared__ unsigned S[256];
  __shared__ unsigned sh_k;
  __shared__ int sh_fall;
  const int tid = threadIdx.x;
  if (tid == 0) {
    long cpos = (long)wsb[OFF_CPOS], cposm = (long)wsb[OFF_CPOSM];
    long cneg = (long)NPIX - cpos;
    long posnum = cpos - cposm;
    long negnum = posnum * 3; if (negnum > cneg) negnum = cneg;
    int fall = (posnum == 0) || (negnum == 0);
    wsb[OFF_NEGNUM] = (unsigned)negnum;
    wsb[OFF_FALL] = (unsigned)fall;
    sh_k = (unsigned)negnum; sh_fall = fall;
    unsigned nvv = 0, vmask = 0;
    for (int k = 1; k < 8; ++k) {
      unsigned kc = wsb[OFF_KC + k], tc = wsb[OFF_TC + k];
      float inv = 1.f / fmaxf((float)kc, 1.f);
      for (int c = 0; c < 4; ++c) wsbf[OFF_G + k * 4 + c] = wsbf[OFF_KS + k * 4 + c] * inv;
      if (kc > 0 && tc > 0) { vmask |= (1u << k); ++nvv; }
    }
    wsb[OFF_NV] = nvv; wsb[OFF_VM] = vmask;
    float s = 0.f;
    for (int i = 1; i < 8; ++i) {
      if (!((vmask >> i) & 1)) continue;
      for (int j = i + 1; j < 8; ++j) {
        if (!((vmask >> j) & 1)) continue;
        float sq = 0.f;
        for (int c = 0; c < 4; ++c) {
          float d = wsbf[OFF_G + i * 4 + c] - wsbf[OFF_G + j * 4 + c];
          sq += d * d;
        }
        float gn = (sq > 0.f) ? sqrtf(sq) : 0.f;
        float dd = fmaxf(3.0f - gn, 0.f);
        s += log1pf(dd * dd);
      }
    }
    float denom = (float)(nvv * (nvv > 0 ? nvv - 1u : 0u));
    wsbf[OFF_LDIS] = (nvv > 1) ? (s / fmaxf(denom, 1.f)) : 0.f;
    if (fall) wsb[OFF_PFX0] = 0xFFFFFFFFu;
  }
  __syncthreads();
  if (sh_fall) return;
  unsigned p = 0;
#pragma unroll
  for (int j = 0; j < 8; ++j) p += wsb[OFF_H0 + tid * 8 + j];
  S[tid] = p;
  __syncthreads();
#pragma unroll
  for (int off = 1; off < 256; off <<= 1) {
    unsigned v = (tid + off < 256) ? S[tid + off] : 0u;
    __syncthreads();
    S[tid] += v;
    __syncthreads();
  }
  unsigned k = sh_k;
  unsigned suf = S[tid];
  unsigned sufn = suf - p;
  if (suf >= k && sufn < k) {
    unsigned kk = k - sufn;
    unsigned cum2 = 0; int bin = tid * 8;
    for (int j = 7; j >= 0; --j) {
      unsigned h = wsb[OFF_H0 + tid * 8 + j]; cum2 += h;
      if (cum2 >= kk) { bin = tid * 8 + j; kk -= (cum2 - h); break; }
    }
    wsb[OFF_PFX0] = (unsigned)bin;
    wsb[OFF_K1] = kk;
  }
}

// -------- pass C2: level-1 histogram from COMPACT key list (205KB/batch) ----
__global__ __launch_bounds__(256) void kC2(unsigned* __restrict__ ws) {
  const int b = blockIdx.y;
  unsigned* wsb = ws + (size_t)b * PER_BATCH;
  if (wsb[OFF_FALL]) return;
  const unsigned pfx = wsb[OFF_PFX0];
  const unsigned kn = wsb[OFF_KN];
  __shared__ unsigned sh_h[2048];
  for (int i = threadIdx.x; i < 2048; i += 256) sh_h[i] = 0u;
  __syncthreads();
  const unsigned* keys = ws + KEYS_BASE + (size_t)b * NPIX;
  for (unsigned i = blockIdx.x * 256 + threadIdx.x; i < kn; i += gridDim.x * 256) {
    unsigned key = keys[i];
    if ((key >> 21) == pfx) atomicAdd(&sh_h[(key >> 10) & 0x7FFu], 1u);
  }
  __syncthreads();
  for (int i = threadIdx.x; i < 2048; i += 256) {
    unsigned v = sh_h[i]; if (v) atomicAdd(&wsb[OFF_H1 + i], v);
  }
}

// ---------------- pass C (fallback): level-1 hist from raw inputs ----------
__global__ __launch_bounds__(256) void kC(const float* __restrict__ out_,
                                          const int* __restrict__ lab_,
                                          unsigned* __restrict__ ws) {
  const int b = blockIdx.y;
  unsigned* wsb = ws + (size_t)b * PER_BATCH;
  if (wsb[OFF_FALL]) return;
  const unsigned pfx = wsb[OFF_PFX0];
  __shared__ unsigned sh_h[2048];
  for (int i = threadIdx.x; i < 2048; i += 256) sh_h[i] = 0u;
  __syncthreads();
  const float4* tx = (const float4*)(out_ + (size_t)b * 6 * NPIX);
  const int4* gt = (const int4*)(lab_ + (size_t)b * 2 * NPIX);
  const int nv = NPIX / 4;
  for (int i = blockIdx.x * blockDim.x + threadIdx.x; i < nv; i += gridDim.x * blockDim.x) {
    float4 t4 = tx[i]; int4 g4 = gt[i];
#pragma unroll
    for (int j = 0; j < 4; ++j) {
      if (((const int*)&g4)[j] <= 0) {
        unsigned key = mapf(((const float*)&t4)[j]);
        if ((key >> 21) == pfx) atomicAdd(&sh_h[(key >> 10) & 0x7FFu], 1u);
      }
    }
  }
  __syncthreads();
  for (int i = threadIdx.x; i < 2048; i += 256) {
    unsigned v = sh_h[i]; if (v) atomicAdd(&wsb[OFF_H1 + i], v);
  }
}

// ---------------- pass D: parallel scan level-1 ----------------
__global__ void kD(unsigned* __restrict__ ws) {
  const int b = blockIdx.x;
  unsigned* wsb = ws + (size_t)b * PER_BATCH;
  if (wsb[OFF_FALL]) return;
  __shared__ unsigned S[256];
  const int tid = threadIdx.x;
  unsigned p = 0;
#pragma unroll
  for (int j = 0; j < 8; ++j) p += wsb[OFF_H1 + tid * 8 + j];
  S[tid] = p;
  __syncthreads();
#pragma unroll
  for (int off = 1; off < 256; off <<= 1) {
    unsigned v = (tid + off < 256) ? S[tid + off] : 0u;
    __syncthreads();
    S[tid] += v;
    __syncthreads();
  }
  unsigned k = wsb[OFF_K1];
  unsigned suf = S[tid];
  unsigned sufn = suf - p;
  if (suf >= k && sufn < k) {
    unsigned kk = k - sufn;
    unsigned cum2 = 0; int bin = tid * 8;
    for (int j = 7; j >= 0; --j) {
      unsigned h = wsb[OFF_H1 + tid * 8 + j]; cum2 += h;
      if (cum2 >= kk) { bin = tid * 8 + j; kk -= (cum2 - h); break; }
    }
    wsb[OFF_PFX1] = (unsigned)bin;
    wsb[OFF_K2] = kk;
  }
}

// -------- pass E2: level-2 histogram from COMPACT key list ----------------
__global__ __launch_bounds__(256) void kE2(unsigned* __restrict__ ws) {
  const int b = blockIdx.y;
  unsigned* wsb = ws + (size_t)b * PER_BATCH;
  if (wsb[OFF_FALL]) return;
  const unsigned pfx22 = (wsb[OFF_PFX0] << 11) | wsb[OFF_PFX1];
  const unsigned kn = wsb[OFF_KN];
  __shared__ unsigned sh_h[1024];
  for (int i = threadIdx.x; i < 1024; i += 256) sh_h[i] = 0u;
  __syncthreads();
  const unsigned* keys = ws + KEYS_BASE + (size_t)b * NPIX;
  for (unsigned i = blockIdx.x * 256 + threadIdx.x; i < kn; i += gridDim.x * 256) {
    unsigned key = keys[i];
    if ((key >> 10) == pfx22) atomicAdd(&sh_h[key & 0x3FFu], 1u);
  }
  __syncthreads();
  for (int i = threadIdx.x; i < 1024; i += 256) {
    unsigned v = sh_h[i]; if (v) atomicAdd(&wsb[OFF_H2 + i], v);
  }
}

// ---------------- pass E (fallback): level-2 hist from raw inputs ----------
__global__ __launch_bounds__(256) void kE(const float* __restrict__ out_,
                                          const int* __restrict__ lab_,
                                          unsigned* __restrict__ ws) {
  const int b = blockIdx.y;
  unsigned* wsb = ws + (size_t)b * PER_BATCH;
  if (wsb[OFF_FALL]) return;
  const unsigned pfx22 = (wsb[OFF_PFX0] << 11) | wsb[OFF_PFX1];
  __shared__ unsigned sh_h[1024];
  for (int i = threadIdx.x; i < 1024; i += 256) sh_h[i] = 0u;
  __syncthreads();
  const float4* tx = (const float4*)(out_ + (size_t)b * 6 * NPIX);
  const int4* gt = (const int4*)(lab_ + (size_t)b * 2 * NPIX);
  const int nv = NPIX / 4;
  for (int i = blockIdx.x * blockDim.x + threadIdx.x; i < nv; i += gridDim.x * blockDim.x) {
    float4 t4 = tx[i]; int4 g4 = gt[i];
#pragma unroll
    for (int j = 0; j < 4; ++j) {
      if (((const int*)&g4)[j] <= 0) {
        unsigned key = mapf(((const float*)&t4)[j]);
        if ((key >> 10) == pfx22) atomicAdd(&sh_h[key & 0x3FFu], 1u);
      }
    }
  }
  __syncthreads();
  for (int i = threadIdx.x; i < 1024; i += 256) {
    unsigned v = sh_h[i]; if (v) atomicAdd(&wsb[OFF_H2 + i], v);
  }
}

// ---------------- pass F: parallel scan level-2 -> threshold ----------------
__global__ void kF(unsigned* __restrict__ ws) {
  const int b = blockIdx.x;
  unsigned* wsb = ws + (size_t)b * PER_BATCH;
  float* wsbf = (float*)wsb;
  const int tid = threadIdx.x;
  if (wsb[OFF_FALL]) { if (tid == 0) wsbf[OFF_TH] = 0.f; return; }
  __shared__ unsigned S[256];
  unsigned p = 0;
#pragma unroll
  for (int j = 0; j < 4; ++j) p += wsb[OFF_H2 + tid * 4 + j];
  S[tid] = p;
  __syncthreads();
#pragma unroll
  for (int off = 1; off < 256; off <<= 1) {
    unsigned v = (tid + off < 256) ? S[tid + off] : 0u;
    __syncthreads();
    S[tid] += v;
    __syncthreads();
  }
  unsigned k = wsb[OFF_K2];
  unsigned suf = S[tid];
  unsigned sufn = suf - p;
  if (suf >= k && sufn < k) {
    unsigned kk = k - sufn;
    unsigned cum2 = 0; int bin = tid * 4;
    for (int j = 3; j >= 0; --j) {
      unsigned h = wsb[OFF_H2 + tid * 4 + j]; cum2 += h;
      if (cum2 >= kk) { bin = tid * 4 + j; break; }
    }
    unsigned key = (wsb[OFF_PFX0] << 21) | (wsb[OFF_PFX1] << 10) | (unsigned)bin;
    wsbf[OFF_TH] = unmapf(key);
  }
}

// ---------------- pass G: agg loss + both dice sums ----------------
__global__ __launch_bounds__(256, 4) void kG(const float* __restrict__ out_,
                                             const int* __restrict__ lab_,
                                             const float* __restrict__ tm_,
                                             unsigned* __restrict__ ws) {
  const int b = blockIdx.y;
  unsigned* wsb = ws + (size_t)b * PER_BATCH;
  float* wsbf = (float*)wsb;
  __shared__ float sG[32];
  __shared__ float sAggR[112];   // [inst 0..6][replica 0..15]
  __shared__ float sD[6];
  __shared__ float sTh;
  __shared__ int sFall;
  const int tid = threadIdx.x;
  const int rep = tid & 15;
  const int lane = tid & 63;
  if (tid < 32) sG[tid] = wsbf[OFF_G + tid];
  for (int i = tid; i < 112; i += 256) sAggR[i] = 0.f;
  if (tid < 6) sD[tid] = 0.f;
  if (tid == 0) { sTh = wsbf[OFF_TH]; sFall = (int)wsb[OFF_FALL]; }
  __syncthreads();
  const float th = sTh;
  const int fall = sFall;

  const float4* tx = (const float4*)(out_ + (size_t)b * 6 * NPIX);
  const float4* kr = (const float4*)(out_ + (size_t)b * 6 * NPIX + (size_t)NPIX);
  const float4* s0 = (const float4*)(out_ + (size_t)b * 6 * NPIX + 2 * (size_t)NPIX);
  const float4* s1 = (const float4*)(out_ + (size_t)b * 6 * NPIX + 3 * (size_t)NPIX);
  const float4* s2 = (const float4*)(out_ + (size_t)b * 6 * NPIX + 4 * (size_t)NPIX);
  const float4* s3 = (const float4*)(out_ + (size_t)b * 6 * NPIX + 5 * (size_t)NPIX);
  const int4* gt = (const int4*)(lab_ + (size_t)b * 2 * NPIX);
  const int4* gk = (const int4*)(lab_ + (size_t)b * 2 * NPIX + NPIX);
  const float4* tmv = (const float4*)(tm_ + (size_t)b * NPIX);

  float at = 0.f, bt = 0.f, ct = 0.f, ak = 0.f, bk = 0.f, ck = 0.f;
#pragma unroll
  for (int it = 0; it < 2; ++it) {
    const int i = it * 51200 + blockIdx.x * 256 + tid;
    float4 t4 = tx[i], q4 = kr[i], m4 = tmv[i];
    int4 g4 = gt[i], k4 = gk[i];
    float4 a0 = s0[i], a1 = s1[i], a2 = s2[i], a3 = s3[i];
#pragma unroll
    for (int j = 0; j < 4; ++j) {
      float tv = ((const float*)&t4)[j];
      float kv = ((const float*)&q4)[j];
      float mv = ((const float*)&m4)[j];
      int gtv = ((const int*)&g4)[j];
      int gkv = ((const int*)&k4)[j];
      bool pos = gtv > 0;
      float st = 1.f / (1.f + expf(-tv));
      float sel = fall ? mv : ((((tv >= th) || pos) && (mv > 0.5f)) ? 1.f : 0.f);
      float p = st * sel;
      float tt = pos ? sel : 0.f;
      at += p * tt; bt += p * p; ct += tt * tt;
      float sk2 = 1.f / (1.f + expf(-kv));
      float selk = ((st > 0.5f) && (mv > 0.5f)) ? 1.f : 0.f;
      float pk = sk2 * selk;
      float tk = (gkv > 0) ? selk : 0.f;
      ak += pk * tk; bk += pk * pk; ck += tk * tk;
      if (pos) {
        int kk = gtv & 7;
        float d0 = ((const float*)&a0)[j] - sG[kk * 4 + 0];
        float d1 = ((const float*)&a1)[j] - sG[kk * 4 + 1];
        float d2 = ((const float*)&a2)[j] - sG[kk * 4 + 2];
        float d3 = ((const float*)&a3)[j] - sG[kk * 4 + 3];
        float sq = d0 * d0 + d1 * d1 + d2 * d2 + d3 * d3;
        float d = (sq > 0.f) ? sqrtf(sq) : 0.f;
        float dd = fmaxf(d - 0.5f, 0.f);
        atomicAdd(&sAggR[(gtv - 1) * 16 + rep], log1pf(dd * dd));
      }
    }
  }

  float f;
  f = wredf(at); if (lane == 0) atomicAdd(&sD[0], f);
  f = wredf(bt); if (lane == 0) atomicAdd(&sD[1], f);
  f = wredf(ct); if (lane == 0) atomicAdd(&sD[2], f);
  f = wredf(ak); if (lane == 0) atomicAdd(&sD[3], f);
  f = wredf(bk); if (lane == 0) atomicAdd(&sD[4], f);
  f = wredf(ck); if (lane == 0) atomicAdd(&sD[5], f);
  __syncthreads();
  if (tid < 7) {
    float s = 0.f;
#pragma unroll
    for (int q = 0; q < 16; ++q) s += sAggR[tid * 16 + q];
    if (s != 0.f) atomicAdd(&wsbf[OFF_AGG + 1 + tid], s);
  } else if (tid >= 16 && tid < 22) {
    atomicAdd(&wsbf[OFF_DICE + (tid - 16)], sD[tid - 16]);
  }
}

// ---------------- pass H: finalize 5 scalars ----------------
__global__ void kH(const unsigned* __restrict__ ws, float* __restrict__ out) {
  __shared__ float sv[4][8];
  const int b = threadIdx.x;
  if (b < 8) {
    const unsigned* wsb = ws + (size_t)b * PER_BATCH;
    const float* wsbf = (const float*)wsb;
    float at = wsbf[OFF_DICE + 0], bt = wsbf[OFF_DICE + 1] + 1e-3f, ct = wsbf[OFF_DICE + 2] + 1e-3f;
    float lt = 1.f - 2.f * at / (bt + ct);
    float ak = wsbf[OFF_DICE + 3], bk = wsbf[OFF_DICE + 4] + 1e-3f, ck = wsbf[OFF_DICE + 5] + 1e-3f;
    float lk = 1.f - 2.f * ak / (bk + ck);
    unsigned vm = wsb[OFF_VM], nvv = wsb[OFF_NV];
    float s = 0.f;
    for (int k = 1; k < 8; ++k)
      if ((vm >> k) & 1) s += wsbf[OFF_AGG + k] / fmaxf((float)wsb[OFF_TC + k], 1.f);
    float la = s / fmaxf((float)nvv, 1.f);
    float ld = wsbf[OFF_LDIS];
    sv[0][b] = lt; sv[1][b] = lk; sv[2][b] = la; sv[3][b] = ld;
  }
  __syncthreads();
  if (threadIdx.x == 0) {
    float mt = 0.f, mk = 0.f, ma = 0.f, md = 0.f;
    for (int i = 0; i < 8; ++i) { mt += sv[0][i]; mk += sv[1][i]; ma += sv[2][i]; md += sv[3][i]; }
    mt *= 0.125f; mk *= 0.125f; ma *= 0.125f; md *= 0.125f;
    out[0] = mt + 0.5f * mk + 0.25f * (ma + md);
    out[1] = mt;
    out[2] = mk;
    out[3] = ma;
    out[4] = md;
  }
}

extern "C" void kernel_launch(void* const* d_in, const int* in_sizes, int n_in,
                              void* d_out, int out_size, void* d_ws, size_t ws_size,
                              hipStream_t stream) {
  const float* outputs = (const float*)d_in[0];
  const int* labels = (const int*)d_in[1];
  const float* tm = (const float*)d_in[2];
  unsigned* ws = (unsigned*)d_ws;
  float* out = (float*)d_out;

  const bool compact = ws_size >= (size_t)(KEYS_BASE + (size_t)NB * NPIX) * 4;

  hipMemsetAsync(d_ws, 0, (size_t)NB * PER_BATCH * sizeof(unsigned), stream);

  dim3 blk(256);
  dim3 gridP(200, NB);  // 1600 blocks, exactly 2 float4-iters/thread
  if (compact) {
    kA<true><<<gridP, blk, 0, stream>>>(outputs, labels, tm, ws);
    kB<<<NB, 256, 0, stream>>>(ws);
    kC2<<<dim3(16, NB), blk, 0, stream>>>(ws);
    kD<<<NB, 256, 0, stream>>>(ws);
    kE2<<<dim3(16, NB), blk, 0, stream>>>(ws);
    kF<<<NB, 256, 0, stream>>>(ws);
  } else {
    kA<false><<<gridP, blk, 0, stream>>>(outputs, labels, tm, ws);
    kB<<<NB, 256, 0, stream>>>(ws);
    kC<<<dim3(128, NB), blk, 0, stream>>>(outputs, labels, ws);
    kD<<<NB, 256, 0, stream>>>(ws);
    kE<<<dim3(128, NB), blk, 0, stream>>>(outputs, labels, ws);
    kF<<<NB, 256, 0, stream>>>(ws);
  }
  kG<<<gridP, blk, 0, stream>>>(outputs, labels, tm, ws);
  kH<<<1, 64, 0, stream>>>(ws, out);
}

// Round 4
// 106.375 us; speedup vs baseline: 1.3562x; 1.3562x over previous
//
#include <hip/hip_runtime.h>

#define NPIX 409600   // 640*640
#define NB 8          // batch

// ---------------- workspace layout (4-byte words, per batch) ----------------
constexpr int OFF_H0    = 0;     // 2048 u32  level-0 histogram (key bits 31..21)
constexpr int OFF_H1    = 2048;  // 2048 u32  level-1 histogram (key bits 20..10)
constexpr int OFF_H2    = 4096;  // 1024 u32  level-2 histogram (key bits 9..0)
constexpr int OFF_KC    = 5120;  // 8 u32     kernel-mask counts per instance
constexpr int OFF_TC    = 5128;  // 8 u32     text-mask counts per instance
constexpr int OFF_KS    = 5136;  // 32 f32    kernel-mask sim sums (inst*4+c)
constexpr int OFF_AGG   = 5168;  // 8 f32     per-instance sum log1p(D)
constexpr int OFF_CPOS  = 5176;  // u32
constexpr int OFF_CPOSM = 5177;  // u32  pos & tm<=0.5
constexpr int OFF_NEGNUM= 5179;  // u32
constexpr int OFF_PFX0  = 5180;  // u32
constexpr int OFF_K1    = 5181;  // u32
constexpr int OFF_PFX1  = 5182;  // u32
constexpr int OFF_K2    = 5183;  // u32
constexpr int OFF_TH    = 5184;  // f32  OHEM threshold
constexpr int OFF_FALL  = 5185;  // u32  fallback flag
constexpr int OFF_G     = 5186;  // 32 f32 centroids
constexpr int OFF_NV    = 5218;  // u32 n_valid
constexpr int OFF_VM    = 5219;  // u32 valid bitmask
constexpr int OFF_LDIS  = 5220;  // f32
constexpr int OFF_DICE  = 5221;  // 6 f32: at,bt,ct,ak,bk,ck
constexpr int OFF_KN    = 5227;  // u32 compact key count
constexpr int PER_BATCH = 5376;  // padded
constexpr int KEYS_BASE = NB * PER_BATCH;  // compact key arrays (words)

__device__ __forceinline__ unsigned mapf(float s) {
  unsigned b = __float_as_uint(s);
  return (b & 0x80000000u) ? ~b : (b | 0x80000000u);
}
__device__ __forceinline__ float unmapf(unsigned u) {
  return __uint_as_float((u & 0x80000000u) ? (u & 0x7FFFFFFFu) : ~u);
}

__device__ __forceinline__ float wredf(float v) {
#pragma unroll
  for (int m = 32; m >= 1; m >>= 1) v += __shfl_xor(v, m, 64);
  return v;
}
__device__ __forceinline__ unsigned wredu(unsigned v) {
#pragma unroll
  for (int m = 32; m >= 1; m >>= 1) v += (unsigned)__shfl_xor((int)v, m, 64);
  return v;
}

// ---- pass X: hist0 + cpos/cposm + tc counts + register-resident compaction --
// Per-thread key slots are STATIC (fully unrolled 2x4) -> stay in VGPRs.
// One block scan + one global atomic per block; no per-pixel serial chains.
template <bool COMPACT>
__global__ __launch_bounds__(256) void kX(const float* __restrict__ out_,
                                          const int* __restrict__ lab_,
                                          const float* __restrict__ tm_,
                                          unsigned* __restrict__ ws) {
  const int b = blockIdx.y;
  unsigned* wsb = ws + (size_t)b * PER_BATCH;
  __shared__ unsigned sh_h[2048];
  __shared__ unsigned sh_scan[256];
  __shared__ unsigned sh_tcw[4 * 7];
  __shared__ unsigned sh_c[2];
  __shared__ unsigned sh_base;
  const int tid = threadIdx.x;
  const int lane = tid & 63;
  const int w = tid >> 6;
  for (int i = tid; i < 2048; i += 256) sh_h[i] = 0u;
  if (tid < 2) sh_c[tid] = 0u;
  __syncthreads();

  const float4* tx = (const float4*)(out_ + (size_t)b * 6 * NPIX);
  const int4* gt = (const int4*)(lab_ + (size_t)b * 2 * NPIX);
  const float4* tmv = (const float4*)(tm_ + (size_t)b * NPIX);

  unsigned cpos = 0, cposm = 0;
  unsigned tcq[7];
#pragma unroll
  for (int k = 0; k < 7; ++k) tcq[k] = 0u;
  unsigned kreg[8];
  unsigned vmask = 0;

  // grid.x = 200 -> 51200 threads/batch, exactly 2 quad-iters each
#pragma unroll
  for (int it = 0; it < 2; ++it) {
    const int i = it * 51200 + blockIdx.x * 256 + tid;
    float4 t4 = tx[i]; int4 g4 = gt[i]; float4 m4 = tmv[i];
#pragma unroll
    for (int j = 0; j < 4; ++j) {
      float tv = ((const float*)&t4)[j];
      int gtv = ((const int*)&g4)[j];
      float mv = ((const float*)&m4)[j];
      bool pos = gtv > 0;
      cpos += pos;
      cposm += (pos && (mv <= 0.5f));
      unsigned key = mapf(tv);
      kreg[it * 4 + j] = key;
      if (!pos) {
        vmask |= (1u << (it * 4 + j));
        atomicAdd(&sh_h[key >> 21], 1u);
      }
#pragma unroll
      for (int k = 0; k < 7; ++k)
        tcq[k] += (unsigned)__popcll(__ballot(gtv == k + 1));
    }
  }

  // counts: wave-reduce -> LDS -> single global atomic
  unsigned r;
  r = wredu(cpos);  if (lane == 0) atomicAdd(&sh_c[0], r);
  r = wredu(cposm); if (lane == 0) atomicAdd(&sh_c[1], r);
  if (lane == 0) {
#pragma unroll
    for (int k = 0; k < 7; ++k) sh_tcw[w * 7 + k] = tcq[k];
  }

  // block scan of per-thread neg counts
  unsigned cnt = (unsigned)__popc(vmask);
  sh_scan[tid] = cnt;
  __syncthreads();
#pragma unroll
  for (int off = 1; off < 256; off <<= 1) {
    unsigned v = (tid >= off) ? sh_scan[tid - off] : 0u;
    __syncthreads();
    sh_scan[tid] += v;
    __syncthreads();
  }
  if (COMPACT) {
    if (tid == 0) sh_base = atomicAdd(&wsb[OFF_KN], sh_scan[255]);
  }
  if (tid < 7) {
    unsigned s = sh_tcw[tid] + sh_tcw[7 + tid] + sh_tcw[14 + tid] + sh_tcw[21 + tid];
    if (s) atomicAdd(&wsb[OFF_TC + 1 + tid], s);
  }
  if (tid == 0) {
    atomicAdd(&wsb[OFF_CPOS], sh_c[0]);
    atomicAdd(&wsb[OFF_CPOSM], sh_c[1]);
  }
  for (int i = tid; i < 2048; i += 256) {
    unsigned v = sh_h[i]; if (v) atomicAdd(&wsb[OFF_H0 + i], v);
  }
  if (COMPACT) {
    __syncthreads();
    unsigned gb = sh_base + sh_scan[tid] - cnt;
    unsigned* keys = ws + KEYS_BASE + (size_t)b * NPIX;
#pragma unroll
    for (int s = 0; s < 8; ++s) {
      if (vmask & (1u << s)) { keys[gb] = kreg[s]; ++gb; }
    }
  }
}

// ---- pass S: per-instance sim sums (ks) + kc counts -------------------------
// Per-thread private LDS float4 slots [idx 0..7][tid pad 257][c 0..3]:
// one ds_read_b128 + 4 adds + ds_write_b128 per pixel, no atomics.
__global__ __launch_bounds__(256) void kS(const float* __restrict__ out_,
                                          const int* __restrict__ lab_,
                                          unsigned* __restrict__ ws) {
  const int b = blockIdx.y;
  unsigned* wsb = ws + (size_t)b * PER_BATCH;
  float* wsbf = (float*)wsb;
  __shared__ __align__(16) float L[8 * 257 * 4];   // 32.9 KB
  __shared__ float L2[32 * 8];
  __shared__ unsigned sh_kcw[4 * 7];
  const int tid = threadIdx.x;
  const int lane = tid & 63;
  const int w = tid >> 6;
  for (int i = tid; i < 8 * 257 * 4; i += 256) L[i] = 0.f;
  __syncthreads();

  const float4* s0 = (const float4*)(out_ + (size_t)b * 6 * NPIX + 2 * (size_t)NPIX);
  const float4* s1 = (const float4*)(out_ + (size_t)b * 6 * NPIX + 3 * (size_t)NPIX);
  const float4* s2 = (const float4*)(out_ + (size_t)b * 6 * NPIX + 4 * (size_t)NPIX);
  const float4* s3 = (const float4*)(out_ + (size_t)b * 6 * NPIX + 5 * (size_t)NPIX);
  const int4* gk = (const int4*)(lab_ + (size_t)b * 2 * NPIX);  // +NPIX below
  const int4* gkk = (const int4*)(lab_ + (size_t)b * 2 * NPIX + NPIX);

  unsigned kcq[7];
#pragma unroll
  for (int k = 0; k < 7; ++k) kcq[k] = 0u;

  const int nv = NPIX / 4;
  for (int i = blockIdx.x * 256 + tid; i < nv; i += gridDim.x * 256) {
    int4 k4 = gkk[i];
    float4 a0 = s0[i], a1 = s1[i], a2 = s2[i], a3 = s3[i];
#pragma unroll
    for (int j = 0; j < 4; ++j) {
      int gkv = ((const int*)&k4)[j];
#pragma unroll
      for (int k = 0; k < 7; ++k)
        kcq[k] += (unsigned)__popcll(__ballot(gkv == k + 1));
      int idx = (gkv > 0) ? (gkv - 1) : 7;   // 7 = trash slot
      float4* slot = (float4*)&L[(idx * 257 + tid) * 4];
      float4 rr = *slot;
      rr.x += ((const float*)&a0)[j];
      rr.y += ((const float*)&a1)[j];
      rr.z += ((const float*)&a2)[j];
      rr.w += ((const float*)&a3)[j];
      *slot = rr;
    }
  }
  (void)gk;

  if (lane == 0) {
#pragma unroll
    for (int k = 0; k < 7; ++k) sh_kcw[w * 7 + k] = kcq[k];
  }
  __syncthreads();
  // reduce [8 idx][256 tid][4 c] -> 32 sums. plane p = c*8+idx.
  {
    int p = tid & 31;           // plane
    int sub = tid >> 5;         // 0..7
    int idx = p & 7, c = p >> 3;
    float part = 0.f;
#pragma unroll
    for (int i = 0; i < 32; ++i) part += L[(idx * 257 + (sub + 8 * i)) * 4 + c];
    L2[p * 8 + sub] = part;
  }
  __syncthreads();
  if (tid < 32) {
    float s = 0.f;
#pragma unroll
    for (int q = 0; q < 8; ++q) s += L2[tid * 8 + q];
    int idx = tid & 7, c = tid >> 3;
    if (idx < 7 && s != 0.f) atomicAdd(&wsbf[OFF_KS + (idx + 1) * 4 + c], s);
  } else if (tid >= 64 && tid < 71) {
    int k = tid - 64;
    unsigned s = sh_kcw[k] + sh_kcw[7 + k] + sh_kcw[14 + k] + sh_kcw[21 + k];
    if (s) atomicAdd(&wsb[OFF_KC + 1 + k], s);
  }
}

// ------- pass B: scalars, centroids, loss_dis, parallel scan level-0 -------
__global__ void kB(unsigned* __restrict__ ws) {
  const int b = blockIdx.x;
  unsigned* wsb = ws + (size_t)b * PER_BATCH;
  float* wsbf = (float*)wsb;
  __shared__ unsigned S[256];
  __shared__ unsigned sh_k;
  __shared__ int sh_fall;
  const int tid = threadIdx.x;
  if (tid == 0) {
    long cpos = (long)wsb[OFF_CPOS], cposm = (long)wsb[OFF_CPOSM];
    long cneg = (long)NPIX - cpos;
    long posnum = cpos - cposm;
    long negnum = posnum * 3; if (negnum > cneg) negnum = cneg;
    int fall = (posnum == 0) || (negnum == 0);
    wsb[OFF_NEGNUM] = (unsigned)negnum;
    wsb[OFF_FALL] = (unsigned)fall;
    sh_k = (unsigned)negnum; sh_fall = fall;
    unsigned nvv = 0, vmask = 0;
    for (int k = 1; k < 8; ++k) {
      unsigned kc = wsb[OFF_KC + k], tc = wsb[OFF_TC + k];
      float inv = 1.f / fmaxf((float)kc, 1.f);
      for (int c = 0; c < 4; ++c) wsbf[OFF_G + k * 4 + c] = wsbf[OFF_KS + k * 4 + c] * inv;
      if (kc > 0 && tc > 0) { vmask |= (1u << k); ++nvv; }
    }
    wsb[OFF_NV] = nvv; wsb[OFF_VM] = vmask;
    float s = 0.f;
    for (int i = 1; i < 8; ++i) {
      if (!((vmask >> i) & 1)) continue;
      for (int j = i + 1; j < 8; ++j) {
        if (!((vmask >> j) & 1)) continue;
        float sq = 0.f;
        for (int c = 0; c < 4; ++c) {
          float d = wsbf[OFF_G + i * 4 + c] - wsbf[OFF_G + j * 4 + c];
          sq += d * d;
        }
        float gn = (sq > 0.f) ? sqrtf(sq) : 0.f;
        float dd = fmaxf(3.0f - gn, 0.f);
        s += log1pf(dd * dd);
      }
    }
    float denom = (float)(nvv * (nvv > 0 ? nvv - 1u : 0u));
    wsbf[OFF_LDIS] = (nvv > 1) ? (s / fmaxf(denom, 1.f)) : 0.f;
    if (fall) wsb[OFF_PFX0] = 0xFFFFFFFFu;
  }
  __syncthreads();
  if (sh_fall) return;
  unsigned p = 0;
#pragma unroll
  for (int j = 0; j < 8; ++j) p += wsb[OFF_H0 + tid * 8 + j];
  S[tid] = p;
  __syncthreads();
#pragma unroll
  for (int off = 1; off < 256; off <<= 1) {
    unsigned v = (tid + off < 256) ? S[tid + off] : 0u;
    __syncthreads();
    S[tid] += v;
    __syncthreads();
  }
  unsigned k = sh_k;
  unsigned suf = S[tid];
  unsigned sufn = suf - p;
  if (suf >= k && sufn < k) {
    unsigned kk = k - sufn;
    unsigned cum2 = 0; int bin = tid * 8;
    for (int j = 7; j >= 0; --j) {
      unsigned h = wsb[OFF_H0 + tid * 8 + j]; cum2 += h;
      if (cum2 >= kk) { bin = tid * 8 + j; kk -= (cum2 - h); break; }
    }
    wsb[OFF_PFX0] = (unsigned)bin;
    wsb[OFF_K1] = kk;
  }
}

// -------- pass C2: level-1 histogram from compact key list ------------------
__global__ __launch_bounds__(256) void kC2(unsigned* __restrict__ ws) {
  const int b = blockIdx.y;
  unsigned* wsb = ws + (size_t)b * PER_BATCH;
  if (wsb[OFF_FALL]) return;
  const unsigned pfx = wsb[OFF_PFX0];
  const unsigned kn = wsb[OFF_KN];
  __shared__ unsigned sh_h[2048];
  for (int i = threadIdx.x; i < 2048; i += 256) sh_h[i] = 0u;
  __syncthreads();
  const unsigned* keys = ws + KEYS_BASE + (size_t)b * NPIX;
  for (unsigned i = blockIdx.x * 256 + threadIdx.x; i < kn; i += gridDim.x * 256) {
    unsigned key = keys[i];
    if ((key >> 21) == pfx) atomicAdd(&sh_h[(key >> 10) & 0x7FFu], 1u);
  }
  __syncthreads();
  for (int i = threadIdx.x; i < 2048; i += 256) {
    unsigned v = sh_h[i]; if (v) atomicAdd(&wsb[OFF_H1 + i], v);
  }
}

// ---------------- pass C (fallback): level-1 hist from raw inputs ----------
__global__ __launch_bounds__(256) void kC(const float* __restrict__ out_,
                                          const int* __restrict__ lab_,
                                          unsigned* __restrict__ ws) {
  const int b = blockIdx.y;
  unsigned* wsb = ws + (size_t)b * PER_BATCH;
  if (wsb[OFF_FALL]) return;
  const unsigned pfx = wsb[OFF_PFX0];
  __shared__ unsigned sh_h[2048];
  for (int i = threadIdx.x; i < 2048; i += 256) sh_h[i] = 0u;
  __syncthreads();
  const float4* tx = (const float4*)(out_ + (size_t)b * 6 * NPIX);
  const int4* gt = (const int4*)(lab_ + (size_t)b * 2 * NPIX);
  const int nv = NPIX / 4;
  for (int i = blockIdx.x * blockDim.x + threadIdx.x; i < nv; i += gridDim.x * blockDim.x) {
    float4 t4 = tx[i]; int4 g4 = gt[i];
#pragma unroll
    for (int j = 0; j < 4; ++j) {
      if (((const int*)&g4)[j] <= 0) {
        unsigned key = mapf(((const float*)&t4)[j]);
        if ((key >> 21) == pfx) atomicAdd(&sh_h[(key >> 10) & 0x7FFu], 1u);
      }
    }
  }
  __syncthreads();
  for (int i = threadIdx.x; i < 2048; i += 256) {
    unsigned v = sh_h[i]; if (v) atomicAdd(&wsb[OFF_H1 + i], v);
  }
}

// ---------------- pass D: parallel scan level-1 ----------------
__global__ void kD(unsigned* __restrict__ ws) {
  const int b = blockIdx.x;
  unsigned* wsb = ws + (size_t)b * PER_BATCH;
  if (wsb[OFF_FALL]) return;
  __shared__ unsigned S[256];
  const int tid = threadIdx.x;
  unsigned p = 0;
#pragma unroll
  for (int j = 0; j < 8; ++j) p += wsb[OFF_H1 + tid * 8 + j];
  S[tid] = p;
  __syncthreads();
#pragma unroll
  for (int off = 1; off < 256; off <<= 1) {
    unsigned v = (tid + off < 256) ? S[tid + off] : 0u;
    __syncthreads();
    S[tid] += v;
    __syncthreads();
  }
  unsigned k = wsb[OFF_K1];
  unsigned suf = S[tid];
  unsigned sufn = suf - p;
  if (suf >= k && sufn < k) {
    unsigned kk = k - sufn;
    unsigned cum2 = 0; int bin = tid * 8;
    for (int j = 7; j >= 0; --j) {
      unsigned h = wsb[OFF_H1 + tid * 8 + j]; cum2 += h;
      if (cum2 >= kk) { bin = tid * 8 + j; kk -= (cum2 - h); break; }
    }
    wsb[OFF_PFX1] = (unsigned)bin;
    wsb[OFF_K2] = kk;
  }
}

// -------- pass E2: level-2 histogram from compact key list ------------------
__global__ __launch_bounds__(256) void kE2(unsigned* __restrict__ ws) {
  const int b = blockIdx.y;
  unsigned* wsb = ws + (size_t)b * PER_BATCH;
  if (wsb[OFF_FALL]) return;
  const unsigned pfx22 = (wsb[OFF_PFX0] << 11) | wsb[OFF_PFX1];
  const unsigned kn = wsb[OFF_KN];
  __shared__ unsigned sh_h[1024];
  for (int i = threadIdx.x; i < 1024; i += 256) sh_h[i] = 0u;
  __syncthreads();
  const unsigned* keys = ws + KEYS_BASE + (size_t)b * NPIX;
  for (unsigned i = blockIdx.x * 256 + threadIdx.x; i < kn; i += gridDim.x * 256) {
    unsigned key = keys[i];
    if ((key >> 10) == pfx22) atomicAdd(&sh_h[key & 0x3FFu], 1u);
  }
  __syncthreads();
  for (int i = threadIdx.x; i < 1024; i += 256) {
    unsigned v = sh_h[i]; if (v) atomicAdd(&wsb[OFF_H2 + i], v);
  }
}

// ---------------- pass E (fallback): level-2 hist from raw inputs ----------
__global__ __launch_bounds__(256) void kE(const float* __restrict__ out_,
                                          const int* __restrict__ lab_,
                                          unsigned* __restrict__ ws) {
  const int b = blockIdx.y;
  unsigned* wsb = ws + (size_t)b * PER_BATCH;
  if (wsb[OFF_FALL]) return;
  const unsigned pfx22 = (wsb[OFF_PFX0] << 11) | wsb[OFF_PFX1];
  __shared__ unsigned sh_h[1024];
  for (int i = threadIdx.x; i < 1024; i += 256) sh_h[i] = 0u;
  __syncthreads();
  const float4* tx = (const float4*)(out_ + (size_t)b * 6 * NPIX);
  const int4* gt = (const int4*)(lab_ + (size_t)b * 2 * NPIX);
  const int nv = NPIX / 4;
  for (int i = blockIdx.x * blockDim.x + threadIdx.x; i < nv; i += gridDim.x * blockDim.x) {
    float4 t4 = tx[i]; int4 g4 = gt[i];
#pragma unroll
    for (int j = 0; j < 4; ++j) {
      if (((const int*)&g4)[j] <= 0) {
        unsigned key = mapf(((const float*)&t4)[j]);
        if ((key >> 10) == pfx22) atomicAdd(&sh_h[key & 0x3FFu], 1u);
      }
    }
  }
  __syncthreads();
  for (int i = threadIdx.x; i < 1024; i += 256) {
    unsigned v = sh_h[i]; if (v) atomicAdd(&wsb[OFF_H2 + i], v);
  }
}

// ---------------- pass F: parallel scan level-2 -> threshold ----------------
__global__ void kF(unsigned* __restrict__ ws) {
  const int b = blockIdx.x;
  unsigned* wsb = ws + (size_t)b * PER_BATCH;
  float* wsbf = (float*)wsb;
  const int tid = threadIdx.x;
  if (wsb[OFF_FALL]) { if (tid == 0) wsbf[OFF_TH] = 0.f; return; }
  __shared__ unsigned S[256];
  unsigned p = 0;
#pragma unroll
  for (int j = 0; j < 4; ++j) p += wsb[OFF_H2 + tid * 4 + j];
  S[tid] = p;
  __syncthreads();
#pragma unroll
  for (int off = 1; off < 256; off <<= 1) {
    unsigned v = (tid + off < 256) ? S[tid + off] : 0u;
    __syncthreads();
    S[tid] += v;
    __syncthreads();
  }
  unsigned k = wsb[OFF_K2];
  unsigned suf = S[tid];
  unsigned sufn = suf - p;
  if (suf >= k && sufn < k) {
    unsigned kk = k - sufn;
    unsigned cum2 = 0; int bin = tid * 4;
    for (int j = 3; j >= 0; --j) {
      unsigned h = wsb[OFF_H2 + tid * 4 + j]; cum2 += h;
      if (cum2 >= kk) { bin = tid * 4 + j; break; }
    }
    unsigned key = (wsb[OFF_PFX0] << 21) | (wsb[OFF_PFX1] << 10) | (unsigned)bin;
    wsbf[OFF_TH] = unmapf(key);
  }
}

// ---------------- pass G: agg loss + both dice sums ----------------
// agg accumulated in per-thread private LDS b32 slots [idx 0..7][257 pad].
__global__ __launch_bounds__(256) void kG(const float* __restrict__ out_,
                                          const int* __restrict__ lab_,
                                          const float* __restrict__ tm_,
                                          unsigned* __restrict__ ws) {
  const int b = blockIdx.y;
  unsigned* wsb = ws + (size_t)b * PER_BATCH;
  float* wsbf = (float*)wsb;
  __shared__ float sG[32];
  __shared__ float LA[8 * 257];   // 8.2 KB
  __shared__ float L2[8 * 33];
  __shared__ float sWred[4 * 6];
  __shared__ float sTh;
  __shared__ int sFall;
  const int tid = threadIdx.x;
  const int lane = tid & 63;
  const int w = tid >> 6;
  if (tid < 32) sG[tid] = wsbf[OFF_G + tid];
  for (int i = tid; i < 8 * 257; i += 256) LA[i] = 0.f;
  if (tid == 0) { sTh = wsbf[OFF_TH]; sFall = (int)wsb[OFF_FALL]; }
  __syncthreads();
  const float th = sTh;
  const int fall = sFall;

  const float4* tx = (const float4*)(out_ + (size_t)b * 6 * NPIX);
  const float4* kr = (const float4*)(out_ + (size_t)b * 6 * NPIX + (size_t)NPIX);
  const float4* s0 = (const float4*)(out_ + (size_t)b * 6 * NPIX + 2 * (size_t)NPIX);
  const float4* s1 = (const float4*)(out_ + (size_t)b * 6 * NPIX + 3 * (size_t)NPIX);
  const float4* s2 = (const float4*)(out_ + (size_t)b * 6 * NPIX + 4 * (size_t)NPIX);
  const float4* s3 = (const float4*)(out_ + (size_t)b * 6 * NPIX + 5 * (size_t)NPIX);
  const int4* gt = (const int4*)(lab_ + (size_t)b * 2 * NPIX);
  const int4* gk = (const int4*)(lab_ + (size_t)b * 2 * NPIX + NPIX);
  const float4* tmv = (const float4*)(tm_ + (size_t)b * NPIX);

  float at = 0.f, bt = 0.f, ct = 0.f, ak = 0.f, bk = 0.f, ck = 0.f;
  const int nv = NPIX / 4;
  for (int i = blockIdx.x * 256 + tid; i < nv; i += gridDim.x * 256) {
    float4 t4 = tx[i], q4 = kr[i], m4 = tmv[i];
    int4 g4 = gt[i], k4 = gk[i];
    float4 a0 = s0[i], a1 = s1[i], a2 = s2[i], a3 = s3[i];
#pragma unroll
    for (int j = 0; j < 4; ++j) {
      float tv = ((const float*)&t4)[j];
      float kv = ((const float*)&q4)[j];
      float mv = ((const float*)&m4)[j];
      int gtv = ((const int*)&g4)[j];
      int gkv = ((const int*)&k4)[j];
      bool pos = gtv > 0;
      float st = 1.f / (1.f + expf(-tv));
      float sel = fall ? mv : ((((tv >= th) || pos) && (mv > 0.5f)) ? 1.f : 0.f);
      float p = st * sel;
      float tt = pos ? sel : 0.f;
      at += p * tt; bt += p * p; ct += tt * tt;
      float sk2 = 1.f / (1.f + expf(-kv));
      float selk = ((st > 0.5f) && (mv > 0.5f)) ? 1.f : 0.f;
      float pk = sk2 * selk;
      float tk = (gkv > 0) ? selk : 0.f;
      ak += pk * tk; bk += pk * pk; ck += tk * tk;
      int idx = pos ? (gtv - 1) : 7;
      int kk = pos ? gtv : 0;
      float d0 = ((const float*)&a0)[j] - sG[kk * 4 + 0];
      float d1 = ((const float*)&a1)[j] - sG[kk * 4 + 1];
      float d2 = ((const float*)&a2)[j] - sG[kk * 4 + 2];
      float d3 = ((const float*)&a3)[j] - sG[kk * 4 + 3];
      float sq = d0 * d0 + d1 * d1 + d2 * d2 + d3 * d3;
      float d = (sq > 0.f) ? sqrtf(sq) : 0.f;
      float dd = fmaxf(d - 0.5f, 0.f);
      float lg = pos ? log1pf(dd * dd) : 0.f;
      LA[idx * 257 + tid] += lg;
    }
  }

  float f;
  f = wredf(at); if (lane == 0) sWred[w * 6 + 0] = f;
  f = wredf(bt); if (lane == 0) sWred[w * 6 + 1] = f;
  f = wredf(ct); if (lane == 0) sWred[w * 6 + 2] = f;
  f = wredf(ak); if (lane == 0) sWred[w * 6 + 3] = f;
  f = wredf(bk); if (lane == 0) sWred[w * 6 + 4] = f;
  f = wredf(ck); if (lane == 0) sWred[w * 6 + 5] = f;
  __syncthreads();
  // reduce LA [8][256] -> 8 sums
  {
    int p = tid & 7, sub = tid >> 3;  // sub 0..31
    float part = 0.f;
#pragma unroll
    for (int i = 0; i < 8; ++i) part += LA[p * 257 + (sub + 32 * i)];
    L2[p * 33 + sub] = part;
  }
  __syncthreads();
  if (tid < 7) {
    float s = 0.f;
#pragma unroll
    for (int q = 0; q < 32; ++q) s += L2[tid * 33 + q];
    if (s != 0.f) atomicAdd(&wsbf[OFF_AGG + 1 + tid], s);
  } else if (tid >= 32 && tid < 38) {
    int c = tid - 32;
    float s = sWred[c] + sWred[6 + c] + sWred[12 + c] + sWred[18 + c];
    atomicAdd(&wsbf[OFF_DICE + c], s);
  }
}

// ---------------- pass H: finalize 5 scalars ----------------
__global__ void kH(const unsigned* __restrict__ ws, float* __restrict__ out) {
  __shared__ float sv[4][8];
  const int b = threadIdx.x;
  if (b < 8) {
    const unsigned* wsb = ws + (size_t)b * PER_BATCH;
    const float* wsbf = (const float*)wsb;
    float at = wsbf[OFF_DICE + 0], bt = wsbf[OFF_DICE + 1] + 1e-3f, ct = wsbf[OFF_DICE + 2] + 1e-3f;
    float lt = 1.f - 2.f * at / (bt + ct);
    float ak = wsbf[OFF_DICE + 3], bk = wsbf[OFF_DICE + 4] + 1e-3f, ck = wsbf[OFF_DICE + 5] + 1e-3f;
    float lk = 1.f - 2.f * ak / (bk + ck);
    unsigned vm = wsb[OFF_VM], nvv = wsb[OFF_NV];
    float s = 0.f;
    for (int k = 1; k < 8; ++k)
      if ((vm >> k) & 1) s += wsbf[OFF_AGG + k] / fmaxf((float)wsb[OFF_TC + k], 1.f);
    float la = s / fmaxf((float)nvv, 1.f);
    float ld = wsbf[OFF_LDIS];
    sv[0][b] = lt; sv[1][b] = lk; sv[2][b] = la; sv[3][b] = ld;
  }
  __syncthreads();
  if (threadIdx.x == 0) {
    float mt = 0.f, mk = 0.f, ma = 0.f, md = 0.f;
    for (int i = 0; i < 8; ++i) { mt += sv[0][i]; mk += sv[1][i]; ma += sv[2][i]; md += sv[3][i]; }
    mt *= 0.125f; mk *= 0.125f; ma *= 0.125f; md *= 0.125f;
    out[0] = mt + 0.5f * mk + 0.25f * (ma + md);
    out[1] = mt;
    out[2] = mk;
    out[3] = ma;
    out[4] = md;
  }
}

extern "C" void kernel_launch(void* const* d_in, const int* in_sizes, int n_in,
                              void* d_out, int out_size, void* d_ws, size_t ws_size,
                              hipStream_t stream) {
  const float* outputs = (const float*)d_in[0];
  const int* labels = (const int*)d_in[1];
  const float* tm = (const float*)d_in[2];
  unsigned* ws = (unsigned*)d_ws;
  float* out = (float*)d_out;

  const bool compact = ws_size >= (size_t)(KEYS_BASE + (size_t)NB * NPIX) * 4;

  hipMemsetAsync(d_ws, 0, (size_t)NB * PER_BATCH * sizeof(unsigned), stream);

  dim3 blk(256);
  if (compact) kX<true><<<dim3(200, NB), blk, 0, stream>>>(outputs, labels, tm, ws);
  else         kX<false><<<dim3(200, NB), blk, 0, stream>>>(outputs, labels, tm, ws);
  kS<<<dim3(128, NB), blk, 0, stream>>>(outputs, labels, ws);
  kB<<<NB, 256, 0, stream>>>(ws);
  if (compact) {
    kC2<<<dim3(16, NB), blk, 0, stream>>>(ws);
    kD<<<NB, 256, 0, stream>>>(ws);
    kE2<<<dim3(16, NB), blk, 0, stream>>>(ws);
  } else {
    kC<<<dim3(128, NB), blk, 0, stream>>>(outputs, labels, ws);
    kD<<<NB, 256, 0, stream>>>(ws);
    kE<<<dim3(128, NB), blk, 0, stream>>>(outputs, labels, ws);
  }
  kF<<<NB, 256, 0, stream>>>(ws);
  kG<<<dim3(128, NB), blk, 0, stream>>>(outputs, labels, tm, ws);
  kH<<<1, 64, 0, stream>>>(ws, out);
}

// Round 5
// 105.789 us; speedup vs baseline: 1.3637x; 1.0055x over previous
//
#include <hip/hip_runtime.h>

#define NPIX 409600   // 640*640
#define NB 8          // batch

// ---------------- workspace layout (4-byte words, per batch) ----------------
constexpr int OFF_H0    = 0;     // 2048 u32  level-0 histogram (key bits 31..21)
constexpr int OFF_H1    = 2048;  // 2048 u32  level-1 histogram (key bits 20..10)
constexpr int OFF_H2    = 4096;  // 1024 u32  level-2 histogram (key bits 9..0)
constexpr int OFF_KC    = 5120;  // 8 u32     kernel-mask counts per instance
constexpr int OFF_TC    = 5128;  // 8 u32     text-mask counts per instance
constexpr int OFF_KS    = 5136;  // 32 f32    kernel-mask sim sums (inst*4+c)
constexpr int OFF_AGG   = 5168;  // 8 f32     per-instance sum log1p(D)
constexpr int OFF_CPOS  = 5176;  // u32
constexpr int OFF_CPOSM = 5177;  // u32  pos & tm<=0.5
constexpr int OFF_NEGNUM= 5179;  // u32
constexpr int OFF_PFX0  = 5180;  // u32
constexpr int OFF_K1    = 5181;  // u32
constexpr int OFF_PFX1  = 5182;  // u32
constexpr int OFF_K2    = 5183;  // u32
constexpr int OFF_TH    = 5184;  // f32  OHEM threshold
constexpr int OFF_FALL  = 5185;  // u32  fallback flag
constexpr int OFF_G     = 5186;  // 32 f32 centroids
constexpr int OFF_NV    = 5218;  // u32 n_valid
constexpr int OFF_VM    = 5219;  // u32 valid bitmask
constexpr int OFF_LDIS  = 5220;  // f32
constexpr int OFF_DICE  = 5221;  // 6 f32: at,bt,ct,ak,bk,ck
constexpr int OFF_KN    = 5227;  // u32 compact key count
constexpr int PER_BATCH = 5376;  // padded
constexpr int KEYS_BASE = NB * PER_BATCH;  // compact key arrays (words)
constexpr int HDR_WORDS = NB * PER_BATCH;  // 43008 words = 168 KB

__device__ __forceinline__ unsigned mapf(float s) {
  unsigned b = __float_as_uint(s);
  return (b & 0x80000000u) ? ~b : (b | 0x80000000u);
}
__device__ __forceinline__ float unmapf(unsigned u) {
  return __uint_as_float((u & 0x80000000u) ? (u & 0x7FFFFFFFu) : ~u);
}

__device__ __forceinline__ float wredf(float v) {
#pragma unroll
  for (int m = 32; m >= 1; m >>= 1) v += __shfl_xor(v, m, 64);
  return v;
}
__device__ __forceinline__ unsigned wredu(unsigned v) {
#pragma unroll
  for (int m = 32; m >= 1; m >>= 1) v += (unsigned)__shfl_xor((int)v, m, 64);
  return v;
}

// ---- pass Z: zero the workspace header (replaces 46us graph-captured fill) --
__global__ __launch_bounds__(256) void kZ(unsigned* __restrict__ ws) {
  int i = blockIdx.x * 256 + threadIdx.x;
  if (i < HDR_WORDS) ws[i] = 0u;
}

// ---- pass X: hist0 + cpos/cposm + tc counts + register-resident compaction --
template <bool COMPACT>
__global__ __launch_bounds__(256) void kX(const float* __restrict__ out_,
                                          const int* __restrict__ lab_,
                                          const float* __restrict__ tm_,
                                          unsigned* __restrict__ ws) {
  const int b = blockIdx.y;
  unsigned* wsb = ws + (size_t)b * PER_BATCH;
  __shared__ unsigned sh_h[2048];
  __shared__ unsigned sh_scan[256];
  __shared__ unsigned sh_tcw[4 * 7];
  __shared__ unsigned sh_c[2];
  __shared__ unsigned sh_base;
  const int tid = threadIdx.x;
  const int lane = tid & 63;
  const int w = tid >> 6;
  for (int i = tid; i < 2048; i += 256) sh_h[i] = 0u;
  if (tid < 2) sh_c[tid] = 0u;
  __syncthreads();

  const float4* tx = (const float4*)(out_ + (size_t)b * 6 * NPIX);
  const int4* gt = (const int4*)(lab_ + (size_t)b * 2 * NPIX);
  const float4* tmv = (const float4*)(tm_ + (size_t)b * NPIX);

  unsigned cpos = 0, cposm = 0;
  unsigned tcq[7];
#pragma unroll
  for (int k = 0; k < 7; ++k) tcq[k] = 0u;
  unsigned kreg[8];
  unsigned vmask = 0;

  // grid.x = 200 -> 51200 threads/batch, exactly 2 quad-iters each
#pragma unroll
  for (int it = 0; it < 2; ++it) {
    const int i = it * 51200 + blockIdx.x * 256 + tid;
    float4 t4 = tx[i]; int4 g4 = gt[i]; float4 m4 = tmv[i];
#pragma unroll
    for (int j = 0; j < 4; ++j) {
      float tv = ((const float*)&t4)[j];
      int gtv = ((const int*)&g4)[j];
      float mv = ((const float*)&m4)[j];
      bool pos = gtv > 0;
      cpos += pos;
      cposm += (pos && (mv <= 0.5f));
      unsigned key = mapf(tv);
      kreg[it * 4 + j] = key;
      if (!pos) {
        vmask |= (1u << (it * 4 + j));
        atomicAdd(&sh_h[key >> 21], 1u);
      }
#pragma unroll
      for (int k = 0; k < 7; ++k)
        tcq[k] += (unsigned)__popcll(__ballot(gtv == k + 1));
    }
  }

  unsigned r;
  r = wredu(cpos);  if (lane == 0) atomicAdd(&sh_c[0], r);
  r = wredu(cposm); if (lane == 0) atomicAdd(&sh_c[1], r);
  if (lane == 0) {
#pragma unroll
    for (int k = 0; k < 7; ++k) sh_tcw[w * 7 + k] = tcq[k];
  }

  unsigned cnt = (unsigned)__popc(vmask);
  sh_scan[tid] = cnt;
  __syncthreads();
#pragma unroll
  for (int off = 1; off < 256; off <<= 1) {
    unsigned v = (tid >= off) ? sh_scan[tid - off] : 0u;
    __syncthreads();
    sh_scan[tid] += v;
    __syncthreads();
  }
  if (COMPACT) {
    if (tid == 0) sh_base = atomicAdd(&wsb[OFF_KN], sh_scan[255]);
  }
  if (tid < 7) {
    unsigned s = sh_tcw[tid] + sh_tcw[7 + tid] + sh_tcw[14 + tid] + sh_tcw[21 + tid];
    if (s) atomicAdd(&wsb[OFF_TC + 1 + tid], s);
  }
  if (tid == 0) {
    atomicAdd(&wsb[OFF_CPOS], sh_c[0]);
    atomicAdd(&wsb[OFF_CPOSM], sh_c[1]);
  }
  for (int i = tid; i < 2048; i += 256) {
    unsigned v = sh_h[i]; if (v) atomicAdd(&wsb[OFF_H0 + i], v);
  }
  if (COMPACT) {
    __syncthreads();
    unsigned gb = sh_base + sh_scan[tid] - cnt;
    unsigned* keys = ws + KEYS_BASE + (size_t)b * NPIX;
#pragma unroll
    for (int s = 0; s < 8; ++s) {
      if (vmask & (1u << s)) { keys[gb] = kreg[s]; ++gb; }
    }
  }
}

// ---- pass S: per-instance sim sums (ks) + kc counts -------------------------
__global__ __launch_bounds__(256) void kS(const float* __restrict__ out_,
                                          const int* __restrict__ lab_,
                                          unsigned* __restrict__ ws) {
  const int b = blockIdx.y;
  unsigned* wsb = ws + (size_t)b * PER_BATCH;
  float* wsbf = (float*)wsb;
  __shared__ __align__(16) float L[8 * 257 * 4];   // 32.9 KB
  __shared__ float L2[32 * 8];
  __shared__ unsigned sh_kcw[4 * 7];
  const int tid = threadIdx.x;
  const int lane = tid & 63;
  const int w = tid >> 6;
  for (int i = tid; i < 8 * 257 * 4; i += 256) L[i] = 0.f;
  __syncthreads();

  const float4* s0 = (const float4*)(out_ + (size_t)b * 6 * NPIX + 2 * (size_t)NPIX);
  const float4* s1 = (const float4*)(out_ + (size_t)b * 6 * NPIX + 3 * (size_t)NPIX);
  const float4* s2 = (const float4*)(out_ + (size_t)b * 6 * NPIX + 4 * (size_t)NPIX);
  const float4* s3 = (const float4*)(out_ + (size_t)b * 6 * NPIX + 5 * (size_t)NPIX);
  const int4* gkk = (const int4*)(lab_ + (size_t)b * 2 * NPIX + NPIX);

  unsigned kcq[7];
#pragma unroll
  for (int k = 0; k < 7; ++k) kcq[k] = 0u;

  const int nv = NPIX / 4;
  for (int i = blockIdx.x * 256 + tid; i < nv; i += gridDim.x * 256) {
    int4 k4 = gkk[i];
    float4 a0 = s0[i], a1 = s1[i], a2 = s2[i], a3 = s3[i];
#pragma unroll
    for (int j = 0; j < 4; ++j) {
      int gkv = ((const int*)&k4)[j];
#pragma unroll
      for (int k = 0; k < 7; ++k)
        kcq[k] += (unsigned)__popcll(__ballot(gkv == k + 1));
      int idx = (gkv > 0) ? (gkv - 1) : 7;   // 7 = trash slot
      float4* slot = (float4*)&L[(idx * 257 + tid) * 4];
      float4 rr = *slot;
      rr.x += ((const float*)&a0)[j];
      rr.y += ((const float*)&a1)[j];
      rr.z += ((const float*)&a2)[j];
      rr.w += ((const float*)&a3)[j];
      *slot = rr;
    }
  }

  if (lane == 0) {
#pragma unroll
    for (int k = 0; k < 7; ++k) sh_kcw[w * 7 + k] = kcq[k];
  }
  __syncthreads();
  {
    int p = tid & 31;           // plane: idx = p&7, c = p>>3
    int sub = tid >> 5;         // 0..7
    int idx = p & 7, c = p >> 3;
    float part = 0.f;
#pragma unroll
    for (int i = 0; i < 32; ++i) part += L[(idx * 257 + (sub + 8 * i)) * 4 + c];
    L2[p * 8 + sub] = part;
  }
  __syncthreads();
  if (tid < 32) {
    float s = 0.f;
#pragma unroll
    for (int q = 0; q < 8; ++q) s += L2[tid * 8 + q];
    int idx = tid & 7, c = tid >> 3;
    if (idx < 7 && s != 0.f) atomicAdd(&wsbf[OFF_KS + (idx + 1) * 4 + c], s);
  } else if (tid >= 64 && tid < 71) {
    int k = tid - 64;
    unsigned s = sh_kcw[k] + sh_kcw[7 + k] + sh_kcw[14 + k] + sh_kcw[21 + k];
    if (s) atomicAdd(&wsb[OFF_KC + 1 + k], s);
  }
}

// ------- pass B: scalars, centroids, loss_dis, parallel scan level-0 -------
__global__ void kB(unsigned* __restrict__ ws) {
  const int b = blockIdx.x;
  unsigned* wsb = ws + (size_t)b * PER_BATCH;
  float* wsbf = (float*)wsb;
  __shared__ unsigned S[256];
  __shared__ unsigned sh_k;
  __shared__ int sh_fall;
  const int tid = threadIdx.x;
  if (tid == 0) {
    long cpos = (long)wsb[OFF_CPOS], cposm = (long)wsb[OFF_CPOSM];
    long cneg = (long)NPIX - cpos;
    long posnum = cpos - cposm;
    long negnum = posnum * 3; if (negnum > cneg) negnum = cneg;
    int fall = (posnum == 0) || (negnum == 0);
    wsb[OFF_NEGNUM] = (unsigned)negnum;
    wsb[OFF_FALL] = (unsigned)fall;
    sh_k = (unsigned)negnum; sh_fall = fall;
    unsigned nvv = 0, vmask = 0;
    for (int k = 1; k < 8; ++k) {
      unsigned kc = wsb[OFF_KC + k], tc = wsb[OFF_TC + k];
      float inv = 1.f / fmaxf((float)kc, 1.f);
      for (int c = 0; c < 4; ++c) wsbf[OFF_G + k * 4 + c] = wsbf[OFF_KS + k * 4 + c] * inv;
      if (kc > 0 && tc > 0) { vmask |= (1u << k); ++nvv; }
    }
    wsb[OFF_NV] = nvv; wsb[OFF_VM] = vmask;
    float s = 0.f;
    for (int i = 1; i < 8; ++i) {
      if (!((vmask >> i) & 1)) continue;
      for (int j = i + 1; j < 8; ++j) {
        if (!((vmask >> j) & 1)) continue;
        float sq = 0.f;
        for (int c = 0; c < 4; ++c) {
          float d = wsbf[OFF_G + i * 4 + c] - wsbf[OFF_G + j * 4 + c];
          sq += d * d;
        }
        float gn = (sq > 0.f) ? sqrtf(sq) : 0.f;
        float dd = fmaxf(3.0f - gn, 0.f);
        s += log1pf(dd * dd);
      }
    }
    float denom = (float)(nvv * (nvv > 0 ? nvv - 1u : 0u));
    wsbf[OFF_LDIS] = (nvv > 1) ? (s / fmaxf(denom, 1.f)) : 0.f;
    if (fall) wsb[OFF_PFX0] = 0xFFFFFFFFu;
  }
  __syncthreads();
  if (sh_fall) return;
  unsigned p = 0;
#pragma unroll
  for (int j = 0; j < 8; ++j) p += wsb[OFF_H0 + tid * 8 + j];
  S[tid] = p;
  __syncthreads();
#pragma unroll
  for (int off = 1; off < 256; off <<= 1) {
    unsigned v = (tid + off < 256) ? S[tid + off] : 0u;
    __syncthreads();
    S[tid] += v;
    __syncthreads();
  }
  unsigned k = sh_k;
  unsigned suf = S[tid];
  unsigned sufn = suf - p;
  if (suf >= k && sufn < k) {
    unsigned kk = k - sufn;
    unsigned cum2 = 0; int bin = tid * 8;
    for (int j = 7; j >= 0; --j) {
      unsigned h = wsb[OFF_H0 + tid * 8 + j]; cum2 += h;
      if (cum2 >= kk) { bin = tid * 8 + j; kk -= (cum2 - h); break; }
    }
    wsb[OFF_PFX0] = (unsigned)bin;
    wsb[OFF_K1] = kk;
  }
}

// -------- pass C2: level-1 histogram from compact key list ------------------
__global__ __launch_bounds__(256) void kC2(unsigned* __restrict__ ws) {
  const int b = blockIdx.y;
  unsigned* wsb = ws + (size_t)b * PER_BATCH;
  if (wsb[OFF_FALL]) return;
  const unsigned pfx = wsb[OFF_PFX0];
  const unsigned kn = wsb[OFF_KN];
  __shared__ unsigned sh_h[2048];
  for (int i = threadIdx.x; i < 2048; i += 256) sh_h[i] = 0u;
  __syncthreads();
  const unsigned* keys = ws + KEYS_BASE + (size_t)b * NPIX;
  for (unsigned i = blockIdx.x * 256 + threadIdx.x; i < kn; i += gridDim.x * 256) {
    unsigned key = keys[i];
    if ((key >> 21) == pfx) atomicAdd(&sh_h[(key >> 10) & 0x7FFu], 1u);
  }
  __syncthreads();
  for (int i = threadIdx.x; i < 2048; i += 256) {
    unsigned v = sh_h[i]; if (v) atomicAdd(&wsb[OFF_H1 + i], v);
  }
}

// ---------------- pass C (fallback): level-1 hist from raw inputs ----------
__global__ __launch_bounds__(256) void kC(const float* __restrict__ out_,
                                          const int* __restrict__ lab_,
                                          unsigned* __restrict__ ws) {
  const int b = blockIdx.y;
  unsigned* wsb = ws + (size_t)b * PER_BATCH;
  if (wsb[OFF_FALL]) return;
  const unsigned pfx = wsb[OFF_PFX0];
  __shared__ unsigned sh_h[2048];
  for (int i = threadIdx.x; i < 2048; i += 256) sh_h[i] = 0u;
  __syncthreads();
  const float4* tx = (const float4*)(out_ + (size_t)b * 6 * NPIX);
  const int4* gt = (const int4*)(lab_ + (size_t)b * 2 * NPIX);
  const int nv = NPIX / 4;
  for (int i = blockIdx.x * blockDim.x + threadIdx.x; i < nv; i += gridDim.x * blockDim.x) {
    float4 t4 = tx[i]; int4 g4 = gt[i];
#pragma unroll
    for (int j = 0; j < 4; ++j) {
      if (((const int*)&g4)[j] <= 0) {
        unsigned key = mapf(((const float*)&t4)[j]);
        if ((key >> 21) == pfx) atomicAdd(&sh_h[(key >> 10) & 0x7FFu], 1u);
      }
    }
  }
  __syncthreads();
  for (int i = threadIdx.x; i < 2048; i += 256) {
    unsigned v = sh_h[i]; if (v) atomicAdd(&wsb[OFF_H1 + i], v);
  }
}

// ---------------- pass D: parallel scan level-1 ----------------
__global__ void kD(unsigned* __restrict__ ws) {
  const int b = blockIdx.x;
  unsigned* wsb = ws + (size_t)b * PER_BATCH;
  if (wsb[OFF_FALL]) return;
  __shared__ unsigned S[256];
  const int tid = threadIdx.x;
  unsigned p = 0;
#pragma unroll
  for (int j = 0; j < 8; ++j) p += wsb[OFF_H1 + tid * 8 + j];
  S[tid] = p;
  __syncthreads();
#pragma unroll
  for (int off = 1; off < 256; off <<= 1) {
    unsigned v = (tid + off < 256) ? S[tid + off] : 0u;
    __syncthreads();
    S[tid] += v;
    __syncthreads();
  }
  unsigned k = wsb[OFF_K1];
  unsigned suf = S[tid];
  unsigned sufn = suf - p;
  if (suf >= k && sufn < k) {
    unsigned kk = k - sufn;
    unsigned cum2 = 0; int bin = tid * 8;
    for (int j = 7; j >= 0; --j) {
      unsigned h = wsb[OFF_H1 + tid * 8 + j]; cum2 += h;
      if (cum2 >= kk) { bin = tid * 8 + j; kk -= (cum2 - h); break; }
    }
    wsb[OFF_PFX1] = (unsigned)bin;
    wsb[OFF_K2] = kk;
  }
}

// -------- pass E2: level-2 histogram from compact key list ------------------
__global__ __launch_bounds__(256) void kE2(unsigned* __restrict__ ws) {
  const int b = blockIdx.y;
  unsigned* wsb = ws + (size_t)b * PER_BATCH;
  if (wsb[OFF_FALL]) return;
  const unsigned pfx22 = (wsb[OFF_PFX0] << 11) | wsb[OFF_PFX1];
  const unsigned kn = wsb[OFF_KN];
  __shared__ unsigned sh_h[1024];
  for (int i = threadIdx.x; i < 1024; i += 256) sh_h[i] = 0u;
  __syncthreads();
  const unsigned* keys = ws + KEYS_BASE + (size_t)b * NPIX;
  for (unsigned i = blockIdx.x * 256 + threadIdx.x; i < kn; i += gridDim.x * 256) {
    unsigned key = keys[i];
    if ((key >> 10) == pfx22) atomicAdd(&sh_h[key & 0x3FFu], 1u);
  }
  __syncthreads();
  for (int i = threadIdx.x; i < 1024; i += 256) {
    unsigned v = sh_h[i]; if (v) atomicAdd(&wsb[OFF_H2 + i], v);
  }
}

// ---------------- pass E (fallback): level-2 hist from raw inputs ----------
__global__ __launch_bounds__(256) void kE(const float* __restrict__ out_,
                                          const int* __restrict__ lab_,
                                          unsigned* __restrict__ ws) {
  const int b = blockIdx.y;
  unsigned* wsb = ws + (size_t)b * PER_BATCH;
  if (wsb[OFF_FALL]) return;
  const unsigned pfx22 = (wsb[OFF_PFX0] << 11) | wsb[OFF_PFX1];
  __shared__ unsigned sh_h[1024];
  for (int i = threadIdx.x; i < 1024; i += 256) sh_h[i] = 0u;
  __syncthreads();
  const float4* tx = (const float4*)(out_ + (size_t)b * 6 * NPIX);
  const int4* gt = (const int4*)(lab_ + (size_t)b * 2 * NPIX);
  const int nv = NPIX / 4;
  for (int i = blockIdx.x * blockDim.x + threadIdx.x; i < nv; i += gridDim.x * blockDim.x) {
    float4 t4 = tx[i]; int4 g4 = gt[i];
#pragma unroll
    for (int j = 0; j < 4; ++j) {
      if (((const int*)&g4)[j] <= 0) {
        unsigned key = mapf(((const float*)&t4)[j]);
        if ((key >> 10) == pfx22) atomicAdd(&sh_h[key & 0x3FFu], 1u);
      }
    }
  }
  __syncthreads();
  for (int i = threadIdx.x; i < 1024; i += 256) {
    unsigned v = sh_h[i]; if (v) atomicAdd(&wsb[OFF_H2 + i], v);
  }
}

// ---------------- pass F: parallel scan level-2 -> threshold ----------------
__global__ void kF(unsigned* __restrict__ ws) {
  const int b = blockIdx.x;
  unsigned* wsb = ws + (size_t)b * PER_BATCH;
  float* wsbf = (float*)wsb;
  const int tid = threadIdx.x;
  if (wsb[OFF_FALL]) { if (tid == 0) wsbf[OFF_TH] = 0.f; return; }
  __shared__ unsigned S[256];
  unsigned p = 0;
#pragma unroll
  for (int j = 0; j < 4; ++j) p += wsb[OFF_H2 + tid * 4 + j];
  S[tid] = p;
  __syncthreads();
#pragma unroll
  for (int off = 1; off < 256; off <<= 1) {
    unsigned v = (tid + off < 256) ? S[tid + off] : 0u;
    __syncthreads();
    S[tid] += v;
    __syncthreads();
  }
  unsigned k = wsb[OFF_K2];
  unsigned suf = S[tid];
  unsigned sufn = suf - p;
  if (suf >= k && sufn < k) {
    unsigned kk = k - sufn;
    unsigned cum2 = 0; int bin = tid * 4;
    for (int j = 3; j >= 0; --j) {
      unsigned h = wsb[OFF_H2 + tid * 4 + j]; cum2 += h;
      if (cum2 >= kk) { bin = tid * 4 + j; break; }
    }
    unsigned key = (wsb[OFF_PFX0] << 21) | (wsb[OFF_PFX1] << 10) | (unsigned)bin;
    wsbf[OFF_TH] = unmapf(key);
  }
}

// ---------------- pass G: agg loss + both dice sums ----------------
__global__ __launch_bounds__(256) void kG(const float* __restrict__ out_,
                                          const int* __restrict__ lab_,
                                          const float* __restrict__ tm_,
                                          unsigned* __restrict__ ws) {
  const int b = blockIdx.y;
  unsigned* wsb = ws + (size_t)b * PER_BATCH;
  float* wsbf = (float*)wsb;
  __shared__ float sG[32];
  __shared__ float LA[8 * 257];   // 8.2 KB
  __shared__ float L2[8 * 33];
  __shared__ float sWred[4 * 6];
  __shared__ float sTh;
  __shared__ int sFall;
  const int tid = threadIdx.x;
  const int lane = tid & 63;
  const int w = tid >> 6;
  if (tid < 32) sG[tid] = wsbf[OFF_G + tid];
  for (int i = tid; i < 8 * 257; i += 256) LA[i] = 0.f;
  if (tid == 0) { sTh = wsbf[OFF_TH]; sFall = (int)wsb[OFF_FALL]; }
  __syncthreads();
  const float th = sTh;
  const int fall = sFall;

  const float4* tx = (const float4*)(out_ + (size_t)b * 6 * NPIX);
  const float4* kr = (const float4*)(out_ + (size_t)b * 6 * NPIX + (size_t)NPIX);
  const float4* s0 = (const float4*)(out_ + (size_t)b * 6 * NPIX + 2 * (size_t)NPIX);
  const float4* s1 = (const float4*)(out_ + (size_t)b * 6 * NPIX + 3 * (size_t)NPIX);
  const float4* s2 = (const float4*)(out_ + (size_t)b * 6 * NPIX + 4 * (size_t)NPIX);
  const float4* s3 = (const float4*)(out_ + (size_t)b * 6 * NPIX + 5 * (size_t)NPIX);
  const int4* gt = (const int4*)(lab_ + (size_t)b * 2 * NPIX);
  const int4* gk = (const int4*)(lab_ + (size_t)b * 2 * NPIX + NPIX);
  const float4* tmv = (const float4*)(tm_ + (size_t)b * NPIX);

  float at = 0.f, bt = 0.f, ct = 0.f, ak = 0.f, bk = 0.f, ck = 0.f;
  const int nv = NPIX / 4;
  for (int i = blockIdx.x * 256 + tid; i < nv; i += gridDim.x * 256) {
    float4 t4 = tx[i], q4 = kr[i], m4 = tmv[i];
    int4 g4 = gt[i], k4 = gk[i];
    float4 a0 = s0[i], a1 = s1[i], a2 = s2[i], a3 = s3[i];
#pragma unroll
    for (int j = 0; j < 4; ++j) {
      float tv = ((const float*)&t4)[j];
      float kv = ((const float*)&q4)[j];
      float mv = ((const float*)&m4)[j];
      int gtv = ((const int*)&g4)[j];
      int gkv = ((const int*)&k4)[j];
      bool pos = gtv > 0;
      float st = 1.f / (1.f + expf(-tv));
      float sel = fall ? mv : ((((tv >= th) || pos) && (mv > 0.5f)) ? 1.f : 0.f);
      float p = st * sel;
      float tt = pos ? sel : 0.f;
      at += p * tt; bt += p * p; ct += tt * tt;
      float sk2 = 1.f / (1.f + expf(-kv));
      float selk = ((st > 0.5f) && (mv > 0.5f)) ? 1.f : 0.f;
      float pk = sk2 * selk;
      float tk = (gkv > 0) ? selk : 0.f;
      ak += pk * tk; bk += pk * pk; ck += tk * tk;
      int idx = pos ? (gtv - 1) : 7;
      int kk = pos ? gtv : 0;
      float d0 = ((const float*)&a0)[j] - sG[kk * 4 + 0];
      float d1 = ((const float*)&a1)[j] - sG[kk * 4 + 1];
      float d2 = ((const float*)&a2)[j] - sG[kk * 4 + 2];
      float d3 = ((const float*)&a3)[j] - sG[kk * 4 + 3];
      float sq = d0 * d0 + d1 * d1 + d2 * d2 + d3 * d3;
      float d = (sq > 0.f) ? sqrtf(sq) : 0.f;
      float dd = fmaxf(d - 0.5f, 0.f);
      float lg = pos ? log1pf(dd * dd) : 0.f;
      LA[idx * 257 + tid] += lg;
    }
  }

  float f;
  f = wredf(at); if (lane == 0) sWred[w * 6 + 0] = f;
  f = wredf(bt); if (lane == 0) sWred[w * 6 + 1] = f;
  f = wredf(ct); if (lane == 0) sWred[w * 6 + 2] = f;
  f = wredf(ak); if (lane == 0) sWred[w * 6 + 3] = f;
  f = wredf(bk); if (lane == 0) sWred[w * 6 + 4] = f;
  f = wredf(ck); if (lane == 0) sWred[w * 6 + 5] = f;
  __syncthreads();
  {
    int p = tid & 7, sub = tid >> 3;  // sub 0..31
    float part = 0.f;
#pragma unroll
    for (int i = 0; i < 8; ++i) part += LA[p * 257 + (sub + 32 * i)];
    L2[p * 33 + sub] = part;
  }
  __syncthreads();
  if (tid < 7) {
    float s = 0.f;
#pragma unroll
    for (int q = 0; q < 32; ++q) s += L2[tid * 33 + q];
    if (s != 0.f) atomicAdd(&wsbf[OFF_AGG + 1 + tid], s);
  } else if (tid >= 32 && tid < 38) {
    int c = tid - 32;
    float s = sWred[c] + sWred[6 + c] + sWred[12 + c] + sWred[18 + c];
    atomicAdd(&wsbf[OFF_DICE + c], s);
  }
}

// ---------------- pass H: finalize 5 scalars ----------------
__global__ void kH(const unsigned* __restrict__ ws, float* __restrict__ out) {
  __shared__ float sv[4][8];
  const int b = threadIdx.x;
  if (b < 8) {
    const unsigned* wsb = ws + (size_t)b * PER_BATCH;
    const float* wsbf = (const float*)wsb;
    float at = wsbf[OFF_DICE + 0], bt = wsbf[OFF_DICE + 1] + 1e-3f, ct = wsbf[OFF_DICE + 2] + 1e-3f;
    float lt = 1.f - 2.f * at / (bt + ct);
    float ak = wsbf[OFF_DICE + 3], bk = wsbf[OFF_DICE + 4] + 1e-3f, ck = wsbf[OFF_DICE + 5] + 1e-3f;
    float lk = 1.f - 2.f * ak / (bk + ck);
    unsigned vm = wsb[OFF_VM], nvv = wsb[OFF_NV];
    float s = 0.f;
    for (int k = 1; k < 8; ++k)
      if ((vm >> k) & 1) s += wsbf[OFF_AGG + k] / fmaxf((float)wsb[OFF_TC + k], 1.f);
    float la = s / fmaxf((float)nvv, 1.f);
    float ld = wsbf[OFF_LDIS];
    sv[0][b] = lt; sv[1][b] = lk; sv[2][b] = la; sv[3][b] = ld;
  }
  __syncthreads();
  if (threadIdx.x == 0) {
    float mt = 0.f, mk = 0.f, ma = 0.f, md = 0.f;
    for (int i = 0; i < 8; ++i) { mt += sv[0][i]; mk += sv[1][i]; ma += sv[2][i]; md += sv[3][i]; }
    mt *= 0.125f; mk *= 0.125f; ma *= 0.125f; md *= 0.125f;
    out[0] = mt + 0.5f * mk + 0.25f * (ma + md);
    out[1] = mt;
    out[2] = mk;
    out[3] = ma;
    out[4] = md;
  }
}

extern "C" void kernel_launch(void* const* d_in, const int* in_sizes, int n_in,
                              void* d_out, int out_size, void* d_ws, size_t ws_size,
                              hipStream_t stream) {
  const float* outputs = (const float*)d_in[0];
  const int* labels = (const int*)d_in[1];
  const float* tm = (const float*)d_in[2];
  unsigned* ws = (unsigned*)d_ws;
  float* out = (float*)d_out;

  const bool compact = ws_size >= (size_t)(KEYS_BASE + (size_t)NB * NPIX) * 4;

  dim3 blk(256);
  kZ<<<(HDR_WORDS + 255) / 256, blk, 0, stream>>>(ws);  // 168 blocks, ~3us
  if (compact) kX<true><<<dim3(200, NB), blk, 0, stream>>>(outputs, labels, tm, ws);
  else         kX<false><<<dim3(200, NB), blk, 0, stream>>>(outputs, labels, tm, ws);
  kS<<<dim3(128, NB), blk, 0, stream>>>(outputs, labels, ws);
  kB<<<NB, 256, 0, stream>>>(ws);
  if (compact) {
    kC2<<<dim3(16, NB), blk, 0, stream>>>(ws);
    kD<<<NB, 256, 0, stream>>>(ws);
    kE2<<<dim3(16, NB), blk, 0, stream>>>(ws);
  } else {
    kC<<<dim3(128, NB), blk, 0, stream>>>(outputs, labels, ws);
    kD<<<NB, 256, 0, stream>>>(ws);
    kE<<<dim3(128, NB), blk, 0, stream>>>(outputs, labels, ws);
  }
  kF<<<NB, 256, 0, stream>>>(ws);
  kG<<<dim3(128, NB), blk, 0, stream>>>(outputs, labels, tm, ws);
  kH<<<1, 64, 0, stream>>>(ws, out);
}